// Round 2
// baseline (753.417 us; speedup 1.0000x reference)
//
#include <hip/hip_runtime.h>
#include <math.h>

typedef unsigned short u16;
typedef __attribute__((ext_vector_type(8))) short short8;
typedef __attribute__((ext_vector_type(8))) unsigned short ushort8;
typedef __attribute__((ext_vector_type(4))) float floatx4;

#define NTOK 4096
#define DDIM 1024
#define FDIM 4096
#define NEXP 8
#define ROWS_PAD 9216   // 8192 + worst-case per-expert 128-padding
#define MTILES 72       // ROWS_PAD / 128

// ---------- bf16 <-> f32 (raw bits, RNE) ----------
__device__ __forceinline__ float b2f(u16 u) {
    union { unsigned u32; float f; } v; v.u32 = ((unsigned)u) << 16; return v.f;
}
__device__ __forceinline__ u16 f2b(float f) {
    union { float f; unsigned u; } v; v.f = f;
    unsigned u = v.u;
    return (u16)((u + 0x7fffu + ((u >> 16) & 1u)) >> 16);
}
__device__ __forceinline__ float bf16r(float f) { return b2f(f2b(f)); }

// ---------------- dtype probe: bf16 vs fp32 input stream ---------------------
// bf16 N(0,0.02) values: exponent field of each uint16 in [90,130] for ~100%.
// fp32 stream read as uint16: only ~56% land in range. Threshold 7400/8192.
__global__ __launch_bounds__(256) void probe_kernel(const u16* __restrict__ wr, int* flag) {
    __shared__ int cnt;
    if (threadIdx.x == 0) cnt = 0;
    __syncthreads();
    int c = 0;
    for (int i = threadIdx.x; i < 8192; i += 256) {
        int e = (wr[i] >> 7) & 0xFF;
        c += (e >= 90 && e <= 130) ? 1 : 0;
    }
    atomicAdd(&cnt, c);
    __syncthreads();
    if (threadIdx.x == 0) *flag = (cnt >= 7400) ? 1 : 0;   // 1 = bf16
}

// ---------------- init: zero row list + counts/cursor ------------------------
__global__ __launch_bounds__(256) void init_kernel(int* row_token, float* row_weight,
                                                   int* counts16) {
    int i = blockIdx.x * 256 + threadIdx.x;
    if (i < ROWS_PAD) { row_token[i] = 0; row_weight[i] = 0.f; }
    if (i < 16) counts16[i] = 0;   // counts[8] + cursor[8]
}

// ---------------- normalize x to bf16 ----------------------------------------
__global__ __launch_bounds__(256) void normx_kernel(const void* __restrict__ xr,
        u16* __restrict__ xb, const int* __restrict__ flag) {
    size_t i = ((size_t)blockIdx.x * 256 + threadIdx.x) * 8;
    if (*flag) {
        *(ushort8*)(xb + i) = *(const ushort8*)((const u16*)xr + i);
    } else {
        const float* xf = (const float*)xr + i;
        floatx4 a = *(const floatx4*)xf;
        floatx4 b = *(const floatx4*)(xf + 4);
        ushort8 o;
#pragma unroll
        for (int l = 0; l < 4; ++l) { o[l] = f2b(a[l]); o[4 + l] = f2b(b[l]); }
        *(ushort8*)(xb + i) = o;
    }
}

// ---------------- router: logits, top-2, softmax ------------------------------
__global__ __launch_bounds__(64) void router_kernel(const void* __restrict__ xr,
        const void* __restrict__ wrr, const int* __restrict__ flag,
        int* __restrict__ tok_e, float* __restrict__ tok_w, int* __restrict__ counts) {
    int t = blockIdx.x;
    int lane = threadIdx.x;
    int isbf = *flag;
    float acc[NEXP];
#pragma unroll
    for (int e = 0; e < NEXP; ++e) acc[e] = 0.f;
    if (isbf) {
        const u16* xrow = (const u16*)xr + (size_t)t * DDIM;
        const u16* wr = (const u16*)wrr;
        for (int j = 0; j < DDIM / 64; ++j) {
            int d = lane + j * 64;
            float xv = b2f(xrow[d]);
            ushort8 wv = *(const ushort8*)(wr + (size_t)d * NEXP);
#pragma unroll
            for (int e = 0; e < NEXP; ++e) acc[e] += xv * b2f(wv[e]);
        }
    } else {
        const float* xrow = (const float*)xr + (size_t)t * DDIM;
        const float* wr = (const float*)wrr;
        for (int j = 0; j < DDIM / 64; ++j) {
            int d = lane + j * 64;
            float xv = xrow[d];
            floatx4 w0 = *(const floatx4*)(wr + (size_t)d * NEXP);
            floatx4 w1 = *(const floatx4*)(wr + (size_t)d * NEXP + 4);
#pragma unroll
            for (int l = 0; l < 4; ++l) { acc[l] += xv * w0[l]; acc[4 + l] += xv * w1[l]; }
        }
    }
#pragma unroll
    for (int off = 32; off > 0; off >>= 1)
#pragma unroll
        for (int e = 0; e < NEXP; ++e) acc[e] += __shfl_xor(acc[e], off, 64);
    if (lane == 0) {
        float v[NEXP];
#pragma unroll
        for (int e = 0; e < NEXP; ++e) v[e] = isbf ? bf16r(acc[e]) : acc[e];
        int e0 = 0;
        for (int e = 1; e < NEXP; ++e) if (v[e] > v[e0]) e0 = e;   // lowest idx wins ties
        int e1 = (e0 == 0) ? 1 : 0;
        for (int e = 0; e < NEXP; ++e) if (e != e0 && v[e] > v[e1]) e1 = e;
        float dlt = expf(v[e1] - v[e0]);           // <= 1
        float w0 = 1.f / (1.f + dlt);
        float w1 = dlt / (1.f + dlt);
        tok_e[2 * t] = e0; tok_e[2 * t + 1] = e1;
        tok_w[2 * t]     = isbf ? bf16r(w0) : w0;
        tok_w[2 * t + 1] = isbf ? bf16r(w1) : w1;
        atomicAdd(&counts[e0], 1);
        atomicAdd(&counts[e1], 1);
    }
}

// ---------------- per-expert offsets, 128-aligned segments --------------------
__global__ void offsets_kernel(const int* counts, int* offs) {
    if (threadIdx.x == 0) {
        int o = 0; offs[0] = 0;
        for (int e = 0; e < NEXP; ++e) { o += ((counts[e] + 127) & ~127); offs[e + 1] = o; }
    }
}

// ---------------- scatter tokens into expert-sorted row list ------------------
__global__ __launch_bounds__(256) void scatter_kernel(const int* __restrict__ tok_e,
        const float* __restrict__ tok_w, const int* __restrict__ offs, int* cursor,
        int* __restrict__ row_token, float* __restrict__ row_weight,
        int* __restrict__ tok_rows) {
    int t = blockIdx.x * 256 + threadIdx.x;
    if (t >= NTOK) return;
#pragma unroll
    for (int k = 0; k < 2; ++k) {
        int e = tok_e[2 * t + k];
        int pos = offs[e] + atomicAdd(&cursor[e], 1);
        row_token[pos] = t;
        row_weight[pos] = tok_w[2 * t + k];
        tok_rows[2 * t + k] = pos;
    }
}

// ---------------- 64x64 tile transpose, dtype-aware src, bf16 dst -------------
__global__ __launch_bounds__(256) void transpose_kernel(const void* __restrict__ src,
        u16* __restrict__ dst, int R, int C, const int* __restrict__ flag) {
    __shared__ u16 tile[64][66];
    int isbf = *flag;
    size_t eoff = (size_t)blockIdx.z * R * C;
    int bc = blockIdx.x * 64;
    int br = blockIdx.y * 64;
    int tid = threadIdx.x;
#pragma unroll
    for (int c = tid; c < 512; c += 256) {
        int r = c >> 3, cc = (c & 7) * 8;
        if (isbf) {
            ushort8 v = *(const ushort8*)((const u16*)src + eoff + (size_t)(br + r) * C + bc + cc);
#pragma unroll
            for (int l = 0; l < 8; ++l) tile[r][cc + l] = v[l];
        } else {
            const float* s = (const float*)src + eoff + (size_t)(br + r) * C + bc + cc;
            floatx4 a = *(const floatx4*)s;
            floatx4 b = *(const floatx4*)(s + 4);
#pragma unroll
            for (int l = 0; l < 4; ++l) { tile[r][cc + l] = f2b(a[l]); tile[r][cc + 4 + l] = f2b(b[l]); }
        }
    }
    __syncthreads();
#pragma unroll
    for (int c = tid; c < 512; c += 256) {
        int i = c >> 3, jj = (c & 7) * 8;
        ushort8 o;
#pragma unroll
        for (int l = 0; l < 8; ++l) o[l] = tile[jj + l][i];
        *(ushort8*)(dst + eoff + (size_t)(bc + i) * R + br + jj) = o;
    }
}

// ---------------- GEMM1: H = gelu(Xb[row_token] @ W1t[e]^T) -------------------
__global__ __launch_bounds__(256) void gemm1_kernel(const u16* __restrict__ X,
        const u16* __restrict__ W1t, u16* __restrict__ H,
        const int* __restrict__ row_token, const int* __restrict__ offs) {
    __shared__ u16 As[128 * 32];
    __shared__ u16 Bs[128 * 32];
    const int tid = threadIdx.x;
    const int m0 = blockIdx.y * 128;
    const int n0 = blockIdx.x * 128;
    if (m0 >= offs[NEXP]) return;   // data-dependent but deterministic; rows never read
    int e = 0;
#pragma unroll
    for (int i = 1; i <= NEXP; ++i) e += (m0 >= offs[i]) ? 1 : 0;
    if (e > 7) e = 7;
    const u16* Bb = W1t + (size_t)e * FDIM * DDIM;
    const int ra = tid >> 2, rb = ra + 64;
    const int cc = (tid & 3) * 8;
    const int tokA = row_token[m0 + ra];
    const int tokB = row_token[m0 + rb];
    const u16* ga0 = X + (size_t)tokA * DDIM + cc;
    const u16* ga1 = X + (size_t)tokB * DDIM + cc;
    const u16* gb0 = Bb + (size_t)(n0 + ra) * DDIM + cc;
    const u16* gb1 = Bb + (size_t)(n0 + rb) * DDIM + cc;
    u16* la0 = &As[tid * 8];
    u16* la1 = &As[(tid + 256) * 8];
    u16* lb0 = &Bs[tid * 8];
    u16* lb1 = &Bs[(tid + 256) * 8];
    const int lane = tid & 63;
    const int wave = tid >> 6;
    const int wm = (wave >> 1) * 64;
    const int wn = (wave & 1) * 64;
    const int lm = lane & 15;
    const int lk = (lane >> 4) * 8;
    floatx4 acc[4][4];
#pragma unroll
    for (int i = 0; i < 4; ++i)
#pragma unroll
        for (int j = 0; j < 4; ++j) acc[i][j] = (floatx4){0.f, 0.f, 0.f, 0.f};
    for (int k0 = 0; k0 < DDIM; k0 += 32) {
        ushort8 va0 = *(const ushort8*)(ga0 + k0);
        ushort8 va1 = *(const ushort8*)(ga1 + k0);
        ushort8 vb0 = *(const ushort8*)(gb0 + k0);
        ushort8 vb1 = *(const ushort8*)(gb1 + k0);
        __syncthreads();                 // prior iteration's frag reads done
        *(ushort8*)la0 = va0;
        *(ushort8*)la1 = va1;
        *(ushort8*)lb0 = vb0;
        *(ushort8*)lb1 = vb1;
        __syncthreads();                 // LDS visible
        short8 af[4], bfr[4];
#pragma unroll
        for (int i = 0; i < 4; ++i) {
            af[i]  = *(const short8*)&As[(wm + i * 16 + lm) * 32 + lk];
            bfr[i] = *(const short8*)&Bs[(wn + i * 16 + lm) * 32 + lk];
        }
#pragma unroll
        for (int i = 0; i < 4; ++i)
#pragma unroll
            for (int j = 0; j < 4; ++j)
                acc[i][j] = __builtin_amdgcn_mfma_f32_16x16x32_bf16(af[i], bfr[j], acc[i][j], 0, 0, 0);
    }
    const int rq = (lane >> 4) * 4;
#pragma unroll
    for (int i = 0; i < 4; ++i)
#pragma unroll
        for (int j = 0; j < 4; ++j)
#pragma unroll
            for (int r = 0; r < 4; ++r) {
                int row = m0 + wm + i * 16 + rq + r;
                int col = n0 + wn + j * 16 + lm;
                float hb = bf16r(acc[i][j][r]);   // ref rounds matmul to bf16 first
                float g = 0.5f * hb * (1.f + erff(hb * 0.70710678118654752f));
                H[(size_t)row * FDIM + col] = f2b(g);
            }
}

// ---------------- GEMM2: Y = H @ W2t[e]^T (bf16, unweighted) ------------------
__global__ __launch_bounds__(256) void gemm2_kernel(const u16* __restrict__ H,
        const u16* __restrict__ W2t, u16* __restrict__ Y, const int* __restrict__ offs) {
    __shared__ u16 As[128 * 32];
    __shared__ u16 Bs[128 * 32];
    const int tid = threadIdx.x;
    const int m0 = blockIdx.y * 128;
    const int n0 = blockIdx.x * 128;
    if (m0 >= offs[NEXP]) return;
    int e = 0;
#pragma unroll
    for (int i = 1; i <= NEXP; ++i) e += (m0 >= offs[i]) ? 1 : 0;
    if (e > 7) e = 7;
    const u16* Bb = W2t + (size_t)e * DDIM * FDIM;
    const int ra = tid >> 2, rb = ra + 64;
    const int cc = (tid & 3) * 8;
    const u16* ga0 = H + (size_t)(m0 + ra) * FDIM + cc;
    const u16* ga1 = H + (size_t)(m0 + rb) * FDIM + cc;
    const u16* gb0 = Bb + (size_t)(n0 + ra) * FDIM + cc;
    const u16* gb1 = Bb + (size_t)(n0 + rb) * FDIM + cc;
    u16* la0 = &As[tid * 8];
    u16* la1 = &As[(tid + 256) * 8];
    u16* lb0 = &Bs[tid * 8];
    u16* lb1 = &Bs[(tid + 256) * 8];
    const int lane = tid & 63;
    const int wave = tid >> 6;
    const int wm = (wave >> 1) * 64;
    const int wn = (wave & 1) * 64;
    const int lm = lane & 15;
    const int lk = (lane >> 4) * 8;
    floatx4 acc[4][4];
#pragma unroll
    for (int i = 0; i < 4; ++i)
#pragma unroll
        for (int j = 0; j < 4; ++j) acc[i][j] = (floatx4){0.f, 0.f, 0.f, 0.f};
    for (int k0 = 0; k0 < FDIM; k0 += 32) {
        ushort8 va0 = *(const ushort8*)(ga0 + k0);
        ushort8 va1 = *(const ushort8*)(ga1 + k0);
        ushort8 vb0 = *(const ushort8*)(gb0 + k0);
        ushort8 vb1 = *(const ushort8*)(gb1 + k0);
        __syncthreads();
        *(ushort8*)la0 = va0;
        *(ushort8*)la1 = va1;
        *(ushort8*)lb0 = vb0;
        *(ushort8*)lb1 = vb1;
        __syncthreads();
        short8 af[4], bfr[4];
#pragma unroll
        for (int i = 0; i < 4; ++i) {
            af[i]  = *(const short8*)&As[(wm + i * 16 + lm) * 32 + lk];
            bfr[i] = *(const short8*)&Bs[(wn + i * 16 + lm) * 32 + lk];
        }
#pragma unroll
        for (int i = 0; i < 4; ++i)
#pragma unroll
            for (int j = 0; j < 4; ++j)
                acc[i][j] = __builtin_amdgcn_mfma_f32_16x16x32_bf16(af[i], bfr[j], acc[i][j], 0, 0, 0);
    }
    const int rq = (lane >> 4) * 4;
#pragma unroll
    for (int i = 0; i < 4; ++i)
#pragma unroll
        for (int j = 0; j < 4; ++j)
#pragma unroll
            for (int r = 0; r < 4; ++r) {
                int row = m0 + wm + i * 16 + rq + r;
                int col = n0 + wn + j * 16 + lm;
                Y[(size_t)row * DDIM + col] = f2b(acc[i][j][r]);   // ref y cast to bf16
            }
}

// ---------------- combine: out[t] = w0*Y[r0] + w1*Y[r1] (fp32 sum) ------------
__global__ __launch_bounds__(256) void combine_kernel(const u16* __restrict__ Y,
        const int* __restrict__ tok_rows, const float* __restrict__ row_weight,
        const int* __restrict__ flag, void* __restrict__ out) {
    int c = blockIdx.x * 256 + threadIdx.x;
    int t = c >> 7;             // D/8 = 128 chunks per token
    int d0 = (c & 127) * 8;
    int r0 = tok_rows[2 * t], r1 = tok_rows[2 * t + 1];
    float w0 = row_weight[r0], w1 = row_weight[r1];
    ushort8 y0 = *(const ushort8*)(Y + (size_t)r0 * DDIM + d0);
    ushort8 y1 = *(const ushort8*)(Y + (size_t)r1 * DDIM + d0);
    float o[8];
#pragma unroll
    for (int l = 0; l < 8; ++l) o[l] = w0 * b2f(y0[l]) + w1 * b2f(y1[l]);
    if (*flag) {
        ushort8 ob;
#pragma unroll
        for (int l = 0; l < 8; ++l) ob[l] = f2b(o[l]);
        *(ushort8*)((u16*)out + (size_t)t * DDIM + d0) = ob;
    } else {
        floatx4 a, b;
#pragma unroll
        for (int l = 0; l < 4; ++l) { a[l] = o[l]; b[l] = o[4 + l]; }
        float* of = (float*)out + (size_t)t * DDIM + d0;
        *(floatx4*)of = a;
        *(floatx4*)(of + 4) = b;
    }
}

extern "C" void kernel_launch(void* const* d_in, const int* in_sizes, int n_in,
                              void* d_out, int out_size, void* d_ws, size_t ws_size,
                              hipStream_t stream) {
    const void* x  = d_in[0];
    const void* Wr = d_in[1];
    const void* W1 = d_in[2];
    const void* W2 = d_in[3];

    char* ws = (char*)d_ws;
    size_t off = 0;
    u16* xb = (u16*)(ws + off); off += (size_t)NTOK * DDIM * 2;            // 8.4 MB
    u16* H  = (u16*)(ws + off); off += (size_t)ROWS_PAD * FDIM * 2;        // 75.5 MB
    u16* WT = (u16*)(ws + off); off += (size_t)NEXP * DDIM * FDIM * 2;     // 67 MB (W1t then W2t)
    u16* Y  = (u16*)(ws + off); off += (size_t)ROWS_PAD * DDIM * 2;        // 18.9 MB
    int*   row_token  = (int*)(ws + off); off += ROWS_PAD * 4;
    float* row_weight = (float*)(ws + off); off += ROWS_PAD * 4;
    int*   tok_e    = (int*)(ws + off); off += NTOK * 2 * 4;
    float* tok_w    = (float*)(ws + off); off += NTOK * 2 * 4;
    int*   tok_rows = (int*)(ws + off); off += NTOK * 2 * 4;
    int*   counts16 = (int*)(ws + off); off += 16 * 4;   // counts[8] + cursor[8]
    int*   offs     = (int*)(ws + off); off += 16 * 4;
    int*   flag     = (int*)(ws + off); off += 4;
    (void)in_sizes; (void)n_in; (void)out_size; (void)ws_size;

    hipLaunchKernelGGL(probe_kernel, dim3(1), dim3(256), 0, stream, (const u16*)Wr, flag);
    hipLaunchKernelGGL(init_kernel, dim3(36), dim3(256), 0, stream,
                       row_token, row_weight, counts16);
    hipLaunchKernelGGL(normx_kernel, dim3(NTOK * DDIM / 8 / 256), dim3(256), 0, stream,
                       x, xb, flag);
    hipLaunchKernelGGL(router_kernel, dim3(NTOK), dim3(64), 0, stream,
                       x, Wr, flag, tok_e, tok_w, counts16);
    hipLaunchKernelGGL(offsets_kernel, dim3(1), dim3(64), 0, stream, counts16, offs);
    hipLaunchKernelGGL(scatter_kernel, dim3(16), dim3(256), 0, stream,
                       tok_e, tok_w, offs, counts16 + 8, row_token, row_weight, tok_rows);
    hipLaunchKernelGGL(transpose_kernel, dim3(FDIM / 64, DDIM / 64, NEXP), dim3(256), 0, stream,
                       W1, WT, DDIM, FDIM, flag);   // [D][F] -> [F][D]
    hipLaunchKernelGGL(gemm1_kernel, dim3(FDIM / 128, MTILES), dim3(256), 0, stream,
                       xb, WT, H, row_token, offs);
    hipLaunchKernelGGL(transpose_kernel, dim3(DDIM / 64, FDIM / 64, NEXP), dim3(256), 0, stream,
                       W2, WT, FDIM, DDIM, flag);   // [F][D] -> [D][F], reuses W1t region
    hipLaunchKernelGGL(gemm2_kernel, dim3(DDIM / 128, MTILES), dim3(256), 0, stream,
                       H, WT, Y, offs);
    hipLaunchKernelGGL(combine_kernel, dim3(NTOK * DDIM / 8 / 256), dim3(256), 0, stream,
                       Y, tok_rows, row_weight, flag, d_out);
}

// Round 3
// 729.990 us; speedup vs baseline: 1.0321x; 1.0321x over previous
//
#include <hip/hip_runtime.h>
#include <math.h>

typedef unsigned short u16;
typedef __attribute__((ext_vector_type(8))) short short8;
typedef __attribute__((ext_vector_type(8))) unsigned short ushort8;
typedef __attribute__((ext_vector_type(4))) float floatx4;

#define NTOK 4096
#define DDIM 1024
#define FDIM 4096
#define NEXP 8
#define ROWS_PAD 9216   // 8192 + worst-case per-expert 128-padding
#define MTILES 72       // ROWS_PAD / 128

// ---------- bf16 <-> f32 (raw bits, RNE) ----------
__device__ __forceinline__ float b2f(u16 u) {
    union { unsigned u32; float f; } v; v.u32 = ((unsigned)u) << 16; return v.f;
}
__device__ __forceinline__ u16 f2b(float f) {
    union { float f; unsigned u; } v; v.f = f;
    unsigned u = v.u;
    return (u16)((u + 0x7fffu + ((u >> 16) & 1u)) >> 16);
}
__device__ __forceinline__ float bf16r(float f) { return b2f(f2b(f)); }

// async global->LDS, 16B per lane. REQUIRED pattern: per-lane LDS ptr equals
// wave-uniform base + lane*16 (our tid*8 u16 layout satisfies this exactly).
__device__ __forceinline__ void async16(const u16* g, u16* l) {
    __builtin_amdgcn_global_load_lds((const __attribute__((address_space(1))) void*)g,
                                     (__attribute__((address_space(3))) void*)l,
                                     16, 0, 0);
}

// ---------------- init + dtype probe ------------------------------------------
// bf16 N(0,0.02) values: exponent field of each uint16 in [90,130] for ~100%.
// fp32 stream read as uint16 pairs: only ~56% land in range. Threshold 7400/8192.
__global__ __launch_bounds__(256) void init_probe_kernel(const u16* __restrict__ wr,
        int* __restrict__ flag, int* __restrict__ row_token,
        float* __restrict__ row_weight, int* __restrict__ counts16) {
    int i = blockIdx.x * 256 + threadIdx.x;
    if (i < ROWS_PAD) { row_token[i] = 0; row_weight[i] = 0.f; }
    if (i < 16) counts16[i] = 0;   // counts[8] + cursor[8]
    if (blockIdx.x == 0) {
        __shared__ int cnt;
        if (threadIdx.x == 0) cnt = 0;
        __syncthreads();
        int c = 0;
        for (int k = threadIdx.x; k < 8192; k += 256) {
            int e = (wr[k] >> 7) & 0xFF;
            c += (e >= 90 && e <= 130) ? 1 : 0;
        }
        atomicAdd(&cnt, c);
        __syncthreads();
        if (threadIdx.x == 0) *flag = (cnt >= 7400) ? 1 : 0;   // 1 = bf16
    }
}

// ---------------- normalize x to bf16 ----------------------------------------
__global__ __launch_bounds__(256) void normx_kernel(const void* __restrict__ xr,
        u16* __restrict__ xb, const int* __restrict__ flag) {
    size_t i = ((size_t)blockIdx.x * 256 + threadIdx.x) * 8;
    if (*flag) {
        *(ushort8*)(xb + i) = *(const ushort8*)((const u16*)xr + i);
    } else {
        const float* xf = (const float*)xr + i;
        floatx4 a = *(const floatx4*)xf;
        floatx4 b = *(const floatx4*)(xf + 4);
        ushort8 o;
#pragma unroll
        for (int l = 0; l < 4; ++l) { o[l] = f2b(a[l]); o[4 + l] = f2b(b[l]); }
        *(ushort8*)(xb + i) = o;
    }
}

// ---------------- router: logits, top-2, softmax ------------------------------
__global__ __launch_bounds__(64) void router_kernel(const void* __restrict__ xr,
        const void* __restrict__ wrr, const int* __restrict__ flag,
        int* __restrict__ tok_e, float* __restrict__ tok_w, int* __restrict__ counts) {
    int t = blockIdx.x;
    int lane = threadIdx.x;
    int isbf = *flag;
    float acc[NEXP];
#pragma unroll
    for (int e = 0; e < NEXP; ++e) acc[e] = 0.f;
    if (isbf) {
        const u16* xrow = (const u16*)xr + (size_t)t * DDIM;
        const u16* wr = (const u16*)wrr;
        for (int j = 0; j < DDIM / 64; ++j) {
            int d = lane + j * 64;
            float xv = b2f(xrow[d]);
            ushort8 wv = *(const ushort8*)(wr + (size_t)d * NEXP);
#pragma unroll
            for (int e = 0; e < NEXP; ++e) acc[e] += xv * b2f(wv[e]);
        }
    } else {
        const float* xrow = (const float*)xr + (size_t)t * DDIM;
        const float* wr = (const float*)wrr;
        for (int j = 0; j < DDIM / 64; ++j) {
            int d = lane + j * 64;
            float xv = xrow[d];
            floatx4 w0 = *(const floatx4*)(wr + (size_t)d * NEXP);
            floatx4 w1 = *(const floatx4*)(wr + (size_t)d * NEXP + 4);
#pragma unroll
            for (int l = 0; l < 4; ++l) { acc[l] += xv * w0[l]; acc[4 + l] += xv * w1[l]; }
        }
    }
#pragma unroll
    for (int off = 32; off > 0; off >>= 1)
#pragma unroll
        for (int e = 0; e < NEXP; ++e) acc[e] += __shfl_xor(acc[e], off, 64);
    if (lane == 0) {
        float v[NEXP];
#pragma unroll
        for (int e = 0; e < NEXP; ++e) v[e] = isbf ? bf16r(acc[e]) : acc[e];
        int e0 = 0;
        for (int e = 1; e < NEXP; ++e) if (v[e] > v[e0]) e0 = e;   // lowest idx wins ties
        int e1 = (e0 == 0) ? 1 : 0;
        for (int e = 0; e < NEXP; ++e) if (e != e0 && v[e] > v[e1]) e1 = e;
        float dlt = expf(v[e1] - v[e0]);           // <= 1
        float w0 = 1.f / (1.f + dlt);
        float w1 = dlt / (1.f + dlt);
        tok_e[2 * t] = e0; tok_e[2 * t + 1] = e1;
        tok_w[2 * t]     = isbf ? bf16r(w0) : w0;
        tok_w[2 * t + 1] = isbf ? bf16r(w1) : w1;
        atomicAdd(&counts[e0], 1);
        atomicAdd(&counts[e1], 1);
    }
}

// ---------------- per-expert offsets, 128-aligned segments --------------------
__global__ void offsets_kernel(const int* counts, int* offs) {
    if (threadIdx.x == 0) {
        int o = 0; offs[0] = 0;
        for (int e = 0; e < NEXP; ++e) { o += ((counts[e] + 127) & ~127); offs[e + 1] = o; }
    }
}

// ---------------- scatter tokens into expert-sorted row list ------------------
__global__ __launch_bounds__(256) void scatter_kernel(const int* __restrict__ tok_e,
        const float* __restrict__ tok_w, const int* __restrict__ offs, int* cursor,
        int* __restrict__ row_token, float* __restrict__ row_weight,
        int* __restrict__ tok_rows) {
    int t = blockIdx.x * 256 + threadIdx.x;
    if (t >= NTOK) return;
#pragma unroll
    for (int k = 0; k < 2; ++k) {
        int e = tok_e[2 * t + k];
        int pos = offs[e] + atomicAdd(&cursor[e], 1);
        row_token[pos] = t;
        row_weight[pos] = tok_w[2 * t + k];
        tok_rows[2 * t + k] = pos;
    }
}

// ---------------- 64x64 tile transpose, dtype-aware src, bf16 dst -------------
__global__ __launch_bounds__(256) void transpose_kernel(const void* __restrict__ src,
        u16* __restrict__ dst, int R, int C, const int* __restrict__ flag) {
    __shared__ u16 tile[64][66];
    int isbf = *flag;
    size_t eoff = (size_t)blockIdx.z * R * C;
    int bc = blockIdx.x * 64;
    int br = blockIdx.y * 64;
    int tid = threadIdx.x;
#pragma unroll
    for (int c = tid; c < 512; c += 256) {
        int r = c >> 3, cc = (c & 7) * 8;
        if (isbf) {
            ushort8 v = *(const ushort8*)((const u16*)src + eoff + (size_t)(br + r) * C + bc + cc);
#pragma unroll
            for (int l = 0; l < 8; ++l) tile[r][cc + l] = v[l];
        } else {
            const float* s = (const float*)src + eoff + (size_t)(br + r) * C + bc + cc;
            floatx4 a = *(const floatx4*)s;
            floatx4 b = *(const floatx4*)(s + 4);
#pragma unroll
            for (int l = 0; l < 4; ++l) { tile[r][cc + l] = f2b(a[l]); tile[r][cc + 4 + l] = f2b(b[l]); }
        }
    }
    __syncthreads();
#pragma unroll
    for (int c = tid; c < 512; c += 256) {
        int i = c >> 3, jj = (c & 7) * 8;
        ushort8 o;
#pragma unroll
        for (int l = 0; l < 8; ++l) o[l] = tile[jj + l][i];
        *(ushort8*)(dst + eoff + (size_t)(bc + i) * R + br + jj) = o;
    }
}

// ---------------- GEMM1: H = gelu(Xb[row_token] @ W1t[e]^T) -------------------
// m97 structure: async global->LDS width=16, 128x128 tile, BK=32, 2-barrier loop
__global__ __launch_bounds__(256) void gemm1_kernel(const u16* __restrict__ X,
        const u16* __restrict__ W1t, u16* __restrict__ H,
        const int* __restrict__ row_token, const int* __restrict__ offs) {
    __shared__ u16 As[128 * 32];
    __shared__ u16 Bs[128 * 32];
    const int tid = threadIdx.x;
    const int m0 = blockIdx.y * 128;
    const int n0 = blockIdx.x * 128;
    if (m0 >= offs[NEXP]) return;   // padded-out tiles: never read downstream
    int e = 0;
#pragma unroll
    for (int i = 1; i <= NEXP; ++i) e += (m0 >= offs[i]) ? 1 : 0;
    if (e > 7) e = 7;
    const u16* Bb = W1t + (size_t)e * FDIM * DDIM;
    const int ra = tid >> 2, rb = ra + 64;
    const int cc = (tid & 3) * 8;
    const int tokA = row_token[m0 + ra];
    const int tokB = row_token[m0 + rb];
    const u16* ga0 = X + (size_t)tokA * DDIM + cc;
    const u16* ga1 = X + (size_t)tokB * DDIM + cc;
    const u16* gb0 = Bb + (size_t)(n0 + ra) * DDIM + cc;
    const u16* gb1 = Bb + (size_t)(n0 + rb) * DDIM + cc;
    u16* la0 = &As[tid * 8];
    u16* la1 = &As[(tid + 256) * 8];
    u16* lb0 = &Bs[tid * 8];
    u16* lb1 = &Bs[(tid + 256) * 8];
    const int lane = tid & 63;
    const int wave = tid >> 6;
    const int wm = (wave >> 1) * 64;
    const int wn = (wave & 1) * 64;
    const int lm = lane & 15;
    const int lk = (lane >> 4) * 8;
    floatx4 acc[4][4];
#pragma unroll
    for (int i = 0; i < 4; ++i)
#pragma unroll
        for (int j = 0; j < 4; ++j) acc[i][j] = (floatx4){0.f, 0.f, 0.f, 0.f};
    for (int k0 = 0; k0 < DDIM; k0 += 32) {
        async16(ga0 + k0, la0);
        async16(ga1 + k0, la1);
        async16(gb0 + k0, lb0);
        async16(gb1 + k0, lb1);
        __syncthreads();                 // drains vmcnt: LDS staging visible
        short8 af[4], bfr[4];
#pragma unroll
        for (int i = 0; i < 4; ++i) {
            af[i]  = *(const short8*)&As[(wm + i * 16 + lm) * 32 + lk];
            bfr[i] = *(const short8*)&Bs[(wn + i * 16 + lm) * 32 + lk];
        }
#pragma unroll
        for (int i = 0; i < 4; ++i)
#pragma unroll
            for (int j = 0; j < 4; ++j)
                acc[i][j] = __builtin_amdgcn_mfma_f32_16x16x32_bf16(af[i], bfr[j], acc[i][j], 0, 0, 0);
        __syncthreads();                 // frag reads done before next staging
    }
    const int rq = (lane >> 4) * 4;
#pragma unroll
    for (int i = 0; i < 4; ++i)
#pragma unroll
        for (int j = 0; j < 4; ++j)
#pragma unroll
            for (int r = 0; r < 4; ++r) {
                int row = m0 + wm + i * 16 + rq + r;
                int col = n0 + wn + j * 16 + lm;
                float hb = bf16r(acc[i][j][r]);   // ref rounds matmul to bf16 first
                float g = 0.5f * hb * (1.f + erff(hb * 0.70710678118654752f));
                H[(size_t)row * FDIM + col] = f2b(g);
            }
}

// ---------------- GEMM2: Y = H @ W2t[e]^T (bf16, unweighted) ------------------
__global__ __launch_bounds__(256) void gemm2_kernel(const u16* __restrict__ H,
        const u16* __restrict__ W2t, u16* __restrict__ Y, const int* __restrict__ offs) {
    __shared__ u16 As[128 * 32];
    __shared__ u16 Bs[128 * 32];
    const int tid = threadIdx.x;
    const int m0 = blockIdx.y * 128;
    const int n0 = blockIdx.x * 128;
    if (m0 >= offs[NEXP]) return;
    int e = 0;
#pragma unroll
    for (int i = 1; i <= NEXP; ++i) e += (m0 >= offs[i]) ? 1 : 0;
    if (e > 7) e = 7;
    const u16* Bb = W2t + (size_t)e * DDIM * FDIM;
    const int ra = tid >> 2, rb = ra + 64;
    const int cc = (tid & 3) * 8;
    const u16* ga0 = H + (size_t)(m0 + ra) * FDIM + cc;
    const u16* ga1 = H + (size_t)(m0 + rb) * FDIM + cc;
    const u16* gb0 = Bb + (size_t)(n0 + ra) * FDIM + cc;
    const u16* gb1 = Bb + (size_t)(n0 + rb) * FDIM + cc;
    u16* la0 = &As[tid * 8];
    u16* la1 = &As[(tid + 256) * 8];
    u16* lb0 = &Bs[tid * 8];
    u16* lb1 = &Bs[(tid + 256) * 8];
    const int lane = tid & 63;
    const int wave = tid >> 6;
    const int wm = (wave >> 1) * 64;
    const int wn = (wave & 1) * 64;
    const int lm = lane & 15;
    const int lk = (lane >> 4) * 8;
    floatx4 acc[4][4];
#pragma unroll
    for (int i = 0; i < 4; ++i)
#pragma unroll
        for (int j = 0; j < 4; ++j) acc[i][j] = (floatx4){0.f, 0.f, 0.f, 0.f};
    for (int k0 = 0; k0 < FDIM; k0 += 32) {
        async16(ga0 + k0, la0);
        async16(ga1 + k0, la1);
        async16(gb0 + k0, lb0);
        async16(gb1 + k0, lb1);
        __syncthreads();
        short8 af[4], bfr[4];
#pragma unroll
        for (int i = 0; i < 4; ++i) {
            af[i]  = *(const short8*)&As[(wm + i * 16 + lm) * 32 + lk];
            bfr[i] = *(const short8*)&Bs[(wn + i * 16 + lm) * 32 + lk];
        }
#pragma unroll
        for (int i = 0; i < 4; ++i)
#pragma unroll
            for (int j = 0; j < 4; ++j)
                acc[i][j] = __builtin_amdgcn_mfma_f32_16x16x32_bf16(af[i], bfr[j], acc[i][j], 0, 0, 0);
        __syncthreads();
    }
    const int rq = (lane >> 4) * 4;
#pragma unroll
    for (int i = 0; i < 4; ++i)
#pragma unroll
        for (int j = 0; j < 4; ++j)
#pragma unroll
            for (int r = 0; r < 4; ++r) {
                int row = m0 + wm + i * 16 + rq + r;
                int col = n0 + wn + j * 16 + lm;
                Y[(size_t)row * DDIM + col] = f2b(acc[i][j][r]);   // ref y cast to bf16
            }
}

// ---------------- combine: out[t] = w0*Y[r0] + w1*Y[r1] (fp32 sum) ------------
__global__ __launch_bounds__(256) void combine_kernel(const u16* __restrict__ Y,
        const int* __restrict__ tok_rows, const float* __restrict__ row_weight,
        const int* __restrict__ flag, void* __restrict__ out) {
    int c = blockIdx.x * 256 + threadIdx.x;
    int t = c >> 7;             // D/8 = 128 chunks per token
    int d0 = (c & 127) * 8;
    int r0 = tok_rows[2 * t], r1 = tok_rows[2 * t + 1];
    float w0 = row_weight[r0], w1 = row_weight[r1];
    ushort8 y0 = *(const ushort8*)(Y + (size_t)r0 * DDIM + d0);
    ushort8 y1 = *(const ushort8*)(Y + (size_t)r1 * DDIM + d0);
    float o[8];
#pragma unroll
    for (int l = 0; l < 8; ++l) o[l] = w0 * b2f(y0[l]) + w1 * b2f(y1[l]);
    if (*flag) {
        ushort8 ob;
#pragma unroll
        for (int l = 0; l < 8; ++l) ob[l] = f2b(o[l]);
        *(ushort8*)((u16*)out + (size_t)t * DDIM + d0) = ob;
    } else {
        floatx4 a, b;
#pragma unroll
        for (int l = 0; l < 4; ++l) { a[l] = o[l]; b[l] = o[4 + l]; }
        float* of = (float*)out + (size_t)t * DDIM + d0;
        *(floatx4*)of = a;
        *(floatx4*)(of + 4) = b;
    }
}

extern "C" void kernel_launch(void* const* d_in, const int* in_sizes, int n_in,
                              void* d_out, int out_size, void* d_ws, size_t ws_size,
                              hipStream_t stream) {
    const void* x  = d_in[0];
    const void* Wr = d_in[1];
    const void* W1 = d_in[2];
    const void* W2 = d_in[3];

    char* ws = (char*)d_ws;
    size_t off = 0;
    u16* xb = (u16*)(ws + off); off += (size_t)NTOK * DDIM * 2;            // 8.4 MB
    u16* H  = (u16*)(ws + off); off += (size_t)ROWS_PAD * FDIM * 2;        // 75.5 MB
    u16* WT = (u16*)(ws + off); off += (size_t)NEXP * DDIM * FDIM * 2;     // 67 MB (W1t then W2t)
    u16* Y  = (u16*)(ws + off); off += (size_t)ROWS_PAD * DDIM * 2;        // 18.9 MB
    int*   row_token  = (int*)(ws + off); off += ROWS_PAD * 4;
    float* row_weight = (float*)(ws + off); off += ROWS_PAD * 4;
    int*   tok_e    = (int*)(ws + off); off += NTOK * 2 * 4;
    float* tok_w    = (float*)(ws + off); off += NTOK * 2 * 4;
    int*   tok_rows = (int*)(ws + off); off += NTOK * 2 * 4;
    int*   counts16 = (int*)(ws + off); off += 16 * 4;   // counts[8] + cursor[8]
    int*   offs     = (int*)(ws + off); off += 16 * 4;
    int*   flag     = (int*)(ws + off); off += 4;
    (void)in_sizes; (void)n_in; (void)out_size; (void)ws_size;

    hipLaunchKernelGGL(init_probe_kernel, dim3(36), dim3(256), 0, stream,
                       (const u16*)Wr, flag, row_token, row_weight, counts16);
    hipLaunchKernelGGL(normx_kernel, dim3(NTOK * DDIM / 8 / 256), dim3(256), 0, stream,
                       x, xb, flag);
    hipLaunchKernelGGL(router_kernel, dim3(NTOK), dim3(64), 0, stream,
                       x, Wr, flag, tok_e, tok_w, counts16);
    hipLaunchKernelGGL(offsets_kernel, dim3(1), dim3(64), 0, stream, counts16, offs);
    hipLaunchKernelGGL(scatter_kernel, dim3(16), dim3(256), 0, stream,
                       tok_e, tok_w, offs, counts16 + 8, row_token, row_weight, tok_rows);
    hipLaunchKernelGGL(transpose_kernel, dim3(FDIM / 64, DDIM / 64, NEXP), dim3(256), 0, stream,
                       W1, WT, DDIM, FDIM, flag);   // [D][F] -> [F][D]
    hipLaunchKernelGGL(gemm1_kernel, dim3(FDIM / 128, MTILES), dim3(256), 0, stream,
                       xb, WT, H, row_token, offs);
    hipLaunchKernelGGL(transpose_kernel, dim3(DDIM / 64, FDIM / 64, NEXP), dim3(256), 0, stream,
                       W2, WT, FDIM, DDIM, flag);   // [F][D] -> [D][F], reuses W1t region
    hipLaunchKernelGGL(gemm2_kernel, dim3(DDIM / 128, MTILES), dim3(256), 0, stream,
                       H, WT, Y, offs);
    hipLaunchKernelGGL(combine_kernel, dim3(NTOK * DDIM / 8 / 256), dim3(256), 0, stream,
                       Y, tok_rows, row_weight, flag, d_out);
}